// Round 9
// baseline (404.087 us; speedup 1.0000x reference)
//
#include <hip/hip_runtime.h>

// ---------------------------------------------------------------------------
// GIN forward on MI355X.
// CSR build (2-level counting sort) -> 3 fully-fused layer kernels:
//   [gather-agg (bf16) -> LDS planes -> GEMM bf16x3 stages -> epilogue].
// Inter-layer features stored as bf16 hi/lo planes (hi gathered, hi+lo self).
// ---------------------------------------------------------------------------

constexpr int NN  = 100000;   // nodes
constexpr int NE  = 1600000;  // edges
constexpr int DIN = 64;
constexpr int HID = 128;
constexpr int LDW = 136;      // LDS plane row stride (shorts)

constexpr int BSH   = 9;      // 512 dsts per bucket
constexpr int NBUCK = 196;    // ceil(NN / 512)
constexpr int NBLK  = 200;    // partition blocks
constexpr int CHUNK = 8000;   // NE / NBLK

typedef __attribute__((ext_vector_type(4))) float f32x4;
typedef __attribute__((ext_vector_type(8))) short bf16x8;
typedef __attribute__((ext_vector_type(8))) unsigned short u16x8;

__device__ __forceinline__ short f2bf(float f) {
    union { float f; unsigned u; } x; x.f = f;
    unsigned r = x.u + 0x7fffu + ((x.u >> 16) & 1u);   // RNE
    return (short)(r >> 16);
}
__device__ __forceinline__ float bf2f(short s) {
    union { unsigned u; float f; } x; x.u = ((unsigned)(unsigned short)s) << 16;
    return x.f;
}
__device__ __forceinline__ float bfu(unsigned short s) {
    union { unsigned u; float f; } x; x.u = ((unsigned)s) << 16;
    return x.f;
}

// Wave-local LDS fence (each wave only touches its own 16-row band after the
// post-agg barrier; wave DS ops complete in order).
__device__ __forceinline__ void wave_lds_fence() {
    __builtin_amdgcn_sched_barrier(0);
    asm volatile("s_waitcnt lgkmcnt(0)" ::: "memory");
    __builtin_amdgcn_sched_barrier(0);
}

__device__ __forceinline__ void mfma3(f32x4& acc, bf16x8 ah, bf16x8 al,
                                      bf16x8 wh, bf16x8 wl) {
    acc = __builtin_amdgcn_mfma_f32_16x16x32_bf16(ah, wh, acc, 0, 0, 0);
    acc = __builtin_amdgcn_mfma_f32_16x16x32_bf16(al, wh, acc, 0, 0, 0);
    acc = __builtin_amdgcn_mfma_f32_16x16x32_bf16(ah, wl, acc, 0, 0, 0);
}

// ---------------------------------------------------------------- CSR build
__global__ __launch_bounds__(256)
void bhist_kernel(const int* __restrict__ eidx, int* __restrict__ bcnt,
                  int* __restrict__ pbase) {
    __shared__ int lh[NBUCK];
    int b = blockIdx.x;
    for (int i = threadIdx.x; i < NBUCK; i += 256) lh[i] = 0;
    __syncthreads();
    int e0 = b * CHUNK;
    for (int i = threadIdx.x; i < CHUNK; i += 256)
        atomicAdd(&lh[eidx[NE + e0 + i] >> BSH], 1);
    __syncthreads();
    for (int i = threadIdx.x; i < NBUCK; i += 256)
        pbase[b * NBUCK + i] = atomicAdd(&bcnt[i], lh[i]);
}

__global__ void bscan_kernel(const int* __restrict__ bcnt, int* __restrict__ bbase,
                             int* __restrict__ offs) {
    __shared__ int lds[256];
    int t = threadIdx.x;
    int v = (t < NBUCK) ? bcnt[t] : 0;
    lds[t] = v; __syncthreads();
    #pragma unroll
    for (int o = 1; o < 256; o <<= 1) {
        int x = (t >= o) ? lds[t - o] : 0;
        __syncthreads();
        lds[t] += x;
        __syncthreads();
    }
    if (t < NBUCK) bbase[t] = lds[t] - v;
    if (t == 0) { bbase[NBUCK] = NE; offs[NN] = NE; }
}

__global__ __launch_bounds__(256)
void part_kernel(const int* __restrict__ eidx, const int* __restrict__ bbase,
                 const int* __restrict__ pbase, int2* __restrict__ tmp) {
    __shared__ int lh[NBUCK], lofs[NBUCK], lcnt[NBUCK], gb[NBUCK];
    __shared__ int sb[256];
    __shared__ int2 lp[CHUNK];
    int b = blockIdx.x;
    int t = threadIdx.x;
    for (int i = t; i < NBUCK; i += 256) { lh[i] = 0; lcnt[i] = 0; }
    __syncthreads();
    int e0 = b * CHUNK;
    for (int i = t; i < CHUNK; i += 256)
        atomicAdd(&lh[eidx[NE + e0 + i] >> BSH], 1);
    __syncthreads();
    {
        int v = (t < NBUCK) ? lh[t] : 0;
        sb[t] = v; __syncthreads();
        #pragma unroll
        for (int o = 1; o < 256; o <<= 1) {
            int x = (t >= o) ? sb[t - o] : 0;
            __syncthreads();
            sb[t] += x;
            __syncthreads();
        }
        if (t < NBUCK) {
            lofs[t] = sb[t] - v;
            gb[t]   = bbase[t] + pbase[b * NBUCK + t];
        }
    }
    __syncthreads();
    for (int i = t; i < CHUNK; i += 256) {
        int s = eidx[e0 + i], d = eidx[NE + e0 + i];
        int bk = d >> BSH;
        int r = atomicAdd(&lcnt[bk], 1);
        lp[lofs[bk] + r] = int2{s, d};
    }
    __syncthreads();
    for (int i = t; i < CHUNK; i += 256) {
        int2 p = lp[i];
        int bk = p.y >> BSH;
        tmp[gb[bk] + (i - lofs[bk])] = p;
    }
}

__global__ __launch_bounds__(512)
void bsort_kernel(const int* __restrict__ bbase, const int2* __restrict__ tmp,
                  int* __restrict__ offs, int* __restrict__ esrc) {
    __shared__ int h[512], lo[512], cnt[512];
    int bk = blockIdx.x;
    int n0 = bk << BSH;
    int lo0 = bbase[bk], hi0 = bbase[bk + 1];
    int t = threadIdx.x;
    h[t] = 0; cnt[t] = 0;
    __syncthreads();
    for (int i = lo0 + t; i < hi0; i += 512)
        atomicAdd(&h[tmp[i].y - n0], 1);
    __syncthreads();
    int v = h[t];
    lo[t] = v; __syncthreads();
    #pragma unroll
    for (int o = 1; o < 512; o <<= 1) {
        int x = (t >= o) ? lo[t - o] : 0;
        __syncthreads();
        lo[t] += x;
        __syncthreads();
    }
    int excl = lo[t] - v;
    __syncthreads();
    lo[t] = excl;
    __syncthreads();
    if (n0 + t < NN) offs[n0 + t] = lo0 + excl;
    for (int i = lo0 + t; i < hi0; i += 512) {
        int2 p = tmp[i];
        int ld = p.y - n0;
        int r = atomicAdd(&cnt[ld], 1);
        esrc[lo0 + lo[ld] + r] = p.x;
    }
}

// ---------------------------------------------------------------- x -> bf16
__global__ void cvt_kernel(const float* __restrict__ x, unsigned short* __restrict__ xb) {
    int i = blockIdx.x * 256 + threadIdx.x;       // ushort8 index
    if (i >= NN * DIN / 8) return;
    const f32x4* p = (const f32x4*)x + (size_t)i * 2;
    f32x4 v0 = p[0], v1 = p[1];
    u16x8 o;
    #pragma unroll
    for (int j = 0; j < 4; ++j) {
        o[j]     = (unsigned short)f2bf(v0[j]);
        o[j + 4] = (unsigned short)f2bf(v1[j]);
    }
    ((u16x8*)xb)[i] = o;
}

// ---------------------------------------------------------------- weight pack
// frag: P[c][nt][lane][j] = bf16( W[c*32 + (lane>>4)*8 + j][nt*16 + (lane&15)] )
__global__ void packall_kernel(const float* __restrict__ W1a, const float* __restrict__ W1b,
                               const float* __restrict__ W2a, const float* __restrict__ W3a,
                               const float* __restrict__ W3b, const float* __restrict__ Wl,
                               short* P1a, short* P1b, short* P2a,
                               short* P3a, short* P3b, short* Pl) {
    const float* W; short* P; int K;
    switch (blockIdx.y) {
        case 0: W = W1a; P = P1a; K = 64;  break;
        case 1: W = W1b; P = P1b; K = 128; break;
        case 2: W = W2a; P = P2a; K = 128; break;
        case 3: W = W3a; P = P3a; K = 128; break;
        case 4: W = W3b; P = P3b; K = 128; break;
        default: W = Wl; P = Pl;  K = 128; break;
    }
    int T = (K / 32) * 8 * 64;
    int idx = blockIdx.x * 256 + threadIdx.x;
    if (idx >= T) return;
    int c  = idx >> 9;
    int nt = (idx >> 6) & 7;
    int l  = idx & 63;
    int col   = nt * 16 + (l & 15);
    int kbase = c * 32 + (l >> 4) * 8;
    bf16x8 hi, lo;
    #pragma unroll
    for (int j = 0; j < 8; ++j) {
        float w = W[(kbase + j) * HID + col];
        short h = f2bf(w);
        hi[j] = h;
        lo[j] = f2bf(w - bf2f(h));
    }
    *(bf16x8*)&P[(size_t)idx * 8]       = hi;
    *(bf16x8*)&P[(size_t)(T + idx) * 8] = lo;
}

// ---------------------------------------------------------------- agg phase
// Aggregate 64 nodes of this block into LDS hi/lo planes.
// D=64: self from fp32 x. D=128: self from hi+lo planes. Gather = hi only.
template<int D>
__device__ __forceinline__ void agg_phase(const float* __restrict__ xf,
                                          const unsigned short* __restrict__ selfh,
                                          const unsigned short* __restrict__ selfl,
                                          const unsigned short* __restrict__ gath,
                                          const int* __restrict__ offs,
                                          const int* __restrict__ esrc,
                                          float eps, short* ph, short* pl,
                                          int blk, int M, int tid) {
    constexpr int TPN = D / 8;                // lanes per node (u16x8 each)
    constexpr int NPS = 256 / TPN;            // nodes per sweep
    const u16x8* g8 = (const u16x8*)gath;
    #pragma unroll
    for (int sweep = 0; sweep < 64 / NPS; ++sweep) {
        int ln = sweep * NPS + tid / TPN;
        int f  = tid % TPN;
        int gn = blk * 64 + ln; if (gn >= M) gn = M - 1;

        f32x4 a0, a1;
        if constexpr (D == 64) {
            const float* xr = xf + (size_t)gn * D + f * 8;
            a0 = *(const f32x4*)xr;
            a1 = *(const f32x4*)(xr + 4);
        } else {
            u16x8 sh = ((const u16x8*)selfh)[(size_t)gn * TPN + f];
            u16x8 sl = ((const u16x8*)selfl)[(size_t)gn * TPN + f];
            #pragma unroll
            for (int j = 0; j < 4; ++j) {
                a0[j] = bfu(sh[j])     + bfu(sl[j]);
                a1[j] = bfu(sh[j + 4]) + bfu(sl[j + 4]);
            }
        }
        a0 *= eps; a1 *= eps;
        f32x4 b0 = (f32x4)0.f, b1 = (f32x4)0.f;

        auto acc8 = [&](u16x8 t, f32x4& x0, f32x4& x1) {
            #pragma unroll
            for (int j = 0; j < 4; ++j) { x0[j] += bfu(t[j]); x1[j] += bfu(t[j + 4]); }
        };

        int k = offs[gn], k1 = offs[gn + 1];
        for (; k + 8 <= k1; k += 8) {
            int s0 = esrc[k+0], s1 = esrc[k+1], s2 = esrc[k+2], s3 = esrc[k+3];
            int s4 = esrc[k+4], s5 = esrc[k+5], s6 = esrc[k+6], s7 = esrc[k+7];
            u16x8 t0 = g8[(size_t)s0*TPN+f], t1 = g8[(size_t)s1*TPN+f];
            u16x8 t2 = g8[(size_t)s2*TPN+f], t3 = g8[(size_t)s3*TPN+f];
            u16x8 t4 = g8[(size_t)s4*TPN+f], t5 = g8[(size_t)s5*TPN+f];
            u16x8 t6 = g8[(size_t)s6*TPN+f], t7 = g8[(size_t)s7*TPN+f];
            acc8(t0, a0, a1); acc8(t1, b0, b1); acc8(t2, a0, a1); acc8(t3, b0, b1);
            acc8(t4, a0, a1); acc8(t5, b0, b1); acc8(t6, a0, a1); acc8(t7, b0, b1);
        }
        for (; k + 2 <= k1; k += 2) {
            u16x8 t0 = g8[(size_t)esrc[k]*TPN+f];
            u16x8 t1 = g8[(size_t)esrc[k+1]*TPN+f];
            acc8(t0, a0, a1); acc8(t1, b0, b1);
        }
        if (k < k1) acc8(g8[(size_t)esrc[k]*TPN+f], a0, a1);
        a0 += b0; a1 += b1;

        bf16x8 hi, lo;
        #pragma unroll
        for (int j = 0; j < 4; ++j) {
            short h;
            h = f2bf(a0[j]); hi[j]   = h; lo[j]   = f2bf(a0[j] - bf2f(h));
            h = f2bf(a1[j]); hi[j+4] = h; lo[j+4] = f2bf(a1[j] - bf2f(h));
        }
        *(bf16x8*)&ph[ln * LDW + f * 8] = hi;
        *(bf16x8*)&pl[ln * LDW + f * 8] = lo;
    }
}

// ---------------------------------------------------------------- GEMM stage
template<int NCH>
__device__ __forceinline__ void stage_from_planes(const short* ph, const short* pl,
                                                  const bf16x8* Pv,
                                                  int lr2, int kgrp, int lane,
                                                  f32x4* acc) {
    constexpr int T = NCH * 8 * 64;
    #pragma unroll
    for (int i = 0; i < 8; ++i) acc[i] = (f32x4)0.0f;
    #pragma unroll
    for (int c = 0; c < NCH; ++c) {
        bf16x8 ah = *(const bf16x8*)&ph[lr2 * LDW + c * 32 + kgrp * 8];
        bf16x8 al = *(const bf16x8*)&pl[lr2 * LDW + c * 32 + kgrp * 8];
        #pragma unroll
        for (int nt = 0; nt < 8; ++nt) {
            int fi = ((c * 8) + nt) * 64 + lane;
            mfma3(acc[nt], ah, al, Pv[fi], Pv[T + fi]);
        }
    }
}

// ---------------------------------------------------------------- layer 1
// agg(x, D=64) -> relu(@W1a+b1a) -> bn(relu(@W1b+b1b)) -> hi/lo planes out
__global__ __launch_bounds__(256)
void layer1_kernel(const float* __restrict__ x, const unsigned short* __restrict__ xbh,
                   const int* __restrict__ offs, const int* __restrict__ esrc,
                   const float* __restrict__ epsp,
                   const short* __restrict__ P1, const float* __restrict__ b1,
                   const short* __restrict__ P2, const float* __restrict__ b2,
                   const float* __restrict__ g, const float* __restrict__ be,
                   const float* __restrict__ m, const float* __restrict__ v,
                   unsigned short* __restrict__ outh, unsigned short* __restrict__ outl,
                   int M) {
    __shared__ short ph[64 * LDW];
    __shared__ short pl[64 * LDW];
    const int tid  = threadIdx.x;
    const int wid  = tid >> 6;
    const int lane = tid & 63;
    const int rlo  = lane & 15;
    const int kgrp = lane >> 4;

    agg_phase<64>(x, nullptr, nullptr, xbh, offs, esrc, 1.0f + *epsp,
                  ph, pl, blockIdx.x, M, tid);
    __syncthreads();

    const int lr2 = wid * 16 + rlo;
    f32x4 acc[8];
    stage_from_planes<2>(ph, pl, (const bf16x8*)P1, lr2, kgrp, lane, acc);
    wave_lds_fence();
    #pragma unroll
    for (int nt = 0; nt < 8; ++nt) {
        int col  = nt * 16 + rlo;
        float bb = b1[col];
        #pragma unroll
        for (int jj = 0; jj < 4; ++jj) {
            int lr = wid * 16 + kgrp * 4 + jj;
            float val = fmaxf(acc[nt][jj] + bb, 0.f);
            short h = f2bf(val);
            ph[lr * LDW + col] = h;
            pl[lr * LDW + col] = f2bf(val - bf2f(h));
        }
    }
    wave_lds_fence();

    stage_from_planes<4>(ph, pl, (const bf16x8*)P2, lr2, kgrp, lane, acc);
    #pragma unroll
    for (int nt = 0; nt < 8; ++nt) {
        int col  = nt * 16 + rlo;
        float bb = b2[col];
        float sv = g[col] * rsqrtf(v[col] + 1e-5f);
        float tv = be[col] - m[col] * sv;
        #pragma unroll
        for (int jj = 0; jj < 4; ++jj) {
            int rr = blockIdx.x * 64 + wid * 16 + kgrp * 4 + jj;
            if (rr < M) {
                float val = fmaxf(acc[nt][jj] + bb, 0.f) * sv + tv;
                short h = f2bf(val);
                outh[(size_t)rr * 128 + col] = (unsigned short)h;
                outl[(size_t)rr * 128 + col] = (unsigned short)f2bf(val - bf2f(h));
            }
        }
    }
}

// ---------------------------------------------------------------- layer 2
// agg(h1, D=128) -> bn(relu(@W2a+b2a)) -> hi/lo planes out
__global__ __launch_bounds__(256)
void layer2_kernel(const unsigned short* __restrict__ inh,
                   const unsigned short* __restrict__ inl,
                   const int* __restrict__ offs, const int* __restrict__ esrc,
                   const float* __restrict__ epsp,
                   const short* __restrict__ P1, const float* __restrict__ b1,
                   const float* __restrict__ g, const float* __restrict__ be,
                   const float* __restrict__ m, const float* __restrict__ v,
                   unsigned short* __restrict__ outh, unsigned short* __restrict__ outl,
                   int M) {
    __shared__ short ph[64 * LDW];
    __shared__ short pl[64 * LDW];
    const int tid  = threadIdx.x;
    const int wid  = tid >> 6;
    const int lane = tid & 63;
    const int rlo  = lane & 15;
    const int kgrp = lane >> 4;

    agg_phase<128>(nullptr, inh, inl, inh, offs, esrc, 1.0f + *epsp,
                   ph, pl, blockIdx.x, M, tid);
    __syncthreads();

    const int lr2 = wid * 16 + rlo;
    f32x4 acc[8];
    stage_from_planes<4>(ph, pl, (const bf16x8*)P1, lr2, kgrp, lane, acc);
    #pragma unroll
    for (int nt = 0; nt < 8; ++nt) {
        int col  = nt * 16 + rlo;
        float bb = b1[col];
        float sv = g[col] * rsqrtf(v[col] + 1e-5f);
        float tv = be[col] - m[col] * sv;
        #pragma unroll
        for (int jj = 0; jj < 4; ++jj) {
            int rr = blockIdx.x * 64 + wid * 16 + kgrp * 4 + jj;
            if (rr < M) {
                float val = fmaxf(acc[nt][jj] + bb, 0.f) * sv + tv;
                short h = f2bf(val);
                outh[(size_t)rr * 128 + col] = (unsigned short)h;
                outl[(size_t)rr * 128 + col] = (unsigned short)f2bf(val - bf2f(h));
            }
        }
    }
}

// ---------------------------------------------------------------- layer 3 + head
// agg(h2) -> relu(@W3a+b3a) -> bn(relu(@W3b+b3b)) -> relu(@Wl+bl).Wf + bf -> out
__global__ __launch_bounds__(256)
void layer3_kernel(const unsigned short* __restrict__ inh,
                   const unsigned short* __restrict__ inl,
                   const int* __restrict__ offs, const int* __restrict__ esrc,
                   const float* __restrict__ epsp,
                   const short* __restrict__ P1, const float* __restrict__ b1,
                   const short* __restrict__ P2, const float* __restrict__ b2,
                   const float* __restrict__ g, const float* __restrict__ be,
                   const float* __restrict__ m, const float* __restrict__ v,
                   const short* __restrict__ Pl, const float* __restrict__ bl,
                   const float* __restrict__ Wf, const float* __restrict__ bf,
                   float* __restrict__ out, int M) {
    __shared__ short ph[64 * LDW];
    __shared__ short pl[64 * LDW];
    const int tid  = threadIdx.x;
    const int wid  = tid >> 6;
    const int lane = tid & 63;
    const int rlo  = lane & 15;
    const int kgrp = lane >> 4;

    agg_phase<128>(nullptr, inh, inl, inh, offs, esrc, 1.0f + *epsp,
                   ph, pl, blockIdx.x, M, tid);
    __syncthreads();

    const int lr2 = wid * 16 + rlo;
    f32x4 acc[8];

    // stage 1: relu(@W3a + b3a) -> planes
    stage_from_planes<4>(ph, pl, (const bf16x8*)P1, lr2, kgrp, lane, acc);
    wave_lds_fence();
    #pragma unroll
    for (int nt = 0; nt < 8; ++nt) {
        int col  = nt * 16 + rlo;
        float bb = b1[col];
        #pragma unroll
        for (int jj = 0; jj < 4; ++jj) {
            int lr = wid * 16 + kgrp * 4 + jj;
            float val = fmaxf(acc[nt][jj] + bb, 0.f);
            short h = f2bf(val);
            ph[lr * LDW + col] = h;
            pl[lr * LDW + col] = f2bf(val - bf2f(h));
        }
    }
    wave_lds_fence();

    // stage 2: bn(relu(@W3b + b3b)) -> planes
    stage_from_planes<4>(ph, pl, (const bf16x8*)P2, lr2, kgrp, lane, acc);
    wave_lds_fence();
    #pragma unroll
    for (int nt = 0; nt < 8; ++nt) {
        int col  = nt * 16 + rlo;
        float bb = b2[col];
        float sv = g[col] * rsqrtf(v[col] + 1e-5f);
        float tv = be[col] - m[col] * sv;
        #pragma unroll
        for (int jj = 0; jj < 4; ++jj) {
            int lr = wid * 16 + kgrp * 4 + jj;
            float val = fmaxf(acc[nt][jj] + bb, 0.f) * sv + tv;
            short h = f2bf(val);
            ph[lr * LDW + col] = h;
            pl[lr * LDW + col] = f2bf(val - bf2f(h));
        }
    }
    wave_lds_fence();

    // stage 3: relu(@Wl + bl) . Wf + bf -> out
    stage_from_planes<4>(ph, pl, (const bf16x8*)Pl, lr2, kgrp, lane, acc);
    float p0 = 0, p1 = 0, p2 = 0, p3 = 0;
    #pragma unroll
    for (int nt = 0; nt < 8; ++nt) {
        int col  = nt * 16 + rlo;
        float bb = bl[col];
        float wv = Wf[col];
        p0 += fmaxf(acc[nt][0] + bb, 0.f) * wv;
        p1 += fmaxf(acc[nt][1] + bb, 0.f) * wv;
        p2 += fmaxf(acc[nt][2] + bb, 0.f) * wv;
        p3 += fmaxf(acc[nt][3] + bb, 0.f) * wv;
    }
    #pragma unroll
    for (int o = 1; o < 16; o <<= 1) {
        p0 += __shfl_xor(p0, o);
        p1 += __shfl_xor(p1, o);
        p2 += __shfl_xor(p2, o);
        p3 += __shfl_xor(p3, o);
    }
    if (rlo == 0) {
        int rbase = blockIdx.x * 64 + wid * 16 + kgrp * 4;
        float bfv = bf[0];
        if (rbase + 0 < M) out[rbase + 0] = p0 + bfv;
        if (rbase + 1 < M) out[rbase + 1] = p1 + bfv;
        if (rbase + 2 < M) out[rbase + 2] = p2 + bfv;
        if (rbase + 3 < M) out[rbase + 3] = p3 + bfv;
    }
}

// ---------------------------------------------------------------------------
extern "C" void kernel_launch(void* const* d_in, const int* in_sizes, int n_in,
                              void* d_out, int out_size, void* d_ws, size_t ws_size,
                              hipStream_t stream) {
    const float* x    = (const float*)d_in[0];
    const int*   eidx = (const int*)d_in[1];
    const float* eps1 = (const float*)d_in[2];
    const float* W1a  = (const float*)d_in[3];
    const float* b1a  = (const float*)d_in[4];
    const float* W1b  = (const float*)d_in[5];
    const float* b1b  = (const float*)d_in[6];
    const float* g1   = (const float*)d_in[7];
    const float* be1  = (const float*)d_in[8];
    const float* m1   = (const float*)d_in[9];
    const float* v1   = (const float*)d_in[10];
    const float* eps2 = (const float*)d_in[11];
    const float* W2a  = (const float*)d_in[12];
    const float* b2a  = (const float*)d_in[13];
    const float* g2   = (const float*)d_in[14];
    const float* be2  = (const float*)d_in[15];
    const float* m2   = (const float*)d_in[16];
    const float* v2   = (const float*)d_in[17];
    const float* eps3 = (const float*)d_in[18];
    const float* W3a  = (const float*)d_in[19];
    const float* b3a  = (const float*)d_in[20];
    const float* W3b  = (const float*)d_in[21];
    const float* b3b  = (const float*)d_in[22];
    const float* g3   = (const float*)d_in[23];
    const float* be3  = (const float*)d_in[24];
    const float* m3   = (const float*)d_in[25];
    const float* v3   = (const float*)d_in[26];
    const float* Wl   = (const float*)d_in[27];
    const float* bl   = (const float*)d_in[28];
    const float* Wf   = (const float*)d_in[29];
    const float* bfp  = (const float*)d_in[30];

    char* ws = (char*)d_ws;
    size_t off = 0;
    auto alloc = [&](size_t bytes) -> void* {
        off = (off + 255) & ~(size_t)255;
        void* p = ws + off;
        off += bytes;
        return p;
    };

    unsigned short* xbh = (unsigned short*)alloc((size_t)NN * DIN * 2);
    unsigned short* hAh = (unsigned short*)alloc((size_t)NN * HID * 2);
    unsigned short* hAl = (unsigned short*)alloc((size_t)NN * HID * 2);
    unsigned short* hBh = (unsigned short*)alloc((size_t)NN * HID * 2);
    unsigned short* hBl = (unsigned short*)alloc((size_t)NN * HID * 2);
    int*   offs   = (int*)alloc((size_t)(NN + 1) * 4);
    int*   esrc   = (int*)alloc((size_t)NE * 4);
    int*   bcnt   = (int*)alloc((size_t)NBUCK * 4);
    int*   bbase  = (int*)alloc((size_t)(NBUCK + 1) * 4);
    int*   pbase  = (int*)alloc((size_t)NBLK * NBUCK * 4);
    short* P1a    = (short*)alloc((size_t)2 * DIN * HID * 2);
    short* P1b    = (short*)alloc((size_t)2 * HID * HID * 2);
    short* P2a    = (short*)alloc((size_t)2 * HID * HID * 2);
    short* P3a    = (short*)alloc((size_t)2 * HID * HID * 2);
    short* P3b    = (short*)alloc((size_t)2 * HID * HID * 2);
    short* Pl     = (short*)alloc((size_t)2 * HID * HID * 2);
    // tmp edge pairs (12.8 MB) alias hAh+hAl (51 MB): only live during CSR
    // build, which completes before layer1 writes them.
    int2*  tmp    = (int2*)hAh;

    const int GRID_F = (NN + 63) / 64;              // 1563 layer blocks

    // ---- CSR build (2-level counting sort)
    hipMemsetAsync(bcnt, 0, (size_t)NBUCK * 4, stream);
    bhist_kernel<<<NBLK, 256, 0, stream>>>(eidx, bcnt, pbase);
    bscan_kernel<<<1, 256, 0, stream>>>(bcnt, bbase, offs);
    part_kernel<<<NBLK, 256, 0, stream>>>(eidx, bbase, pbase, tmp);
    bsort_kernel<<<NBUCK, 512, 0, stream>>>(bbase, tmp, offs, esrc);

    // ---- pack weights + bf16 x
    {
        dim3 grid(8, 6);
        packall_kernel<<<grid, 256, 0, stream>>>(W1a, W1b, W2a, W3a, W3b, Wl,
                                                 P1a, P1b, P2a, P3a, P3b, Pl);
    }
    cvt_kernel<<<(NN * DIN / 8 + 255) / 256, 256, 0, stream>>>(x, xbh);

    // ---- layers (fully fused agg+GEMM)
    layer1_kernel<<<GRID_F, 256, 0, stream>>>(x, xbh, offs, esrc, eps1,
                                              P1a, b1a, P1b, b1b,
                                              g1, be1, m1, v1, hAh, hAl, NN);
    layer2_kernel<<<GRID_F, 256, 0, stream>>>(hAh, hAl, offs, esrc, eps2,
                                              P2a, b2a, g2, be2, m2, v2,
                                              hBh, hBl, NN);
    layer3_kernel<<<GRID_F, 256, 0, stream>>>(hBh, hBl, offs, esrc, eps3,
                                              P3a, b3a, P3b, b3b,
                                              g3, be3, m3, v3, Pl, bl, Wf, bfp,
                                              (float*)d_out, NN);
}

// Round 10
// 365.930 us; speedup vs baseline: 1.1043x; 1.1043x over previous
//
#include <hip/hip_runtime.h>

// ---------------------------------------------------------------------------
// GIN forward on MI355X.  (r7 structure + pipelined-index agg)
// CSR build (2-level counting sort) -> [agg (bf16 gather) -> GEMM bf16x3] x3.
// Fused kernels: 128 thr / 64 rows, each wave processes TWO 16-row tiles per
// W-fragment load. aggb: next-iteration indices prefetched during gathers.
// ---------------------------------------------------------------------------

constexpr int NN  = 100000;   // nodes
constexpr int NE  = 1600000;  // edges
constexpr int DIN = 64;
constexpr int HID = 128;

constexpr int BSH   = 9;      // 512 dsts per bucket
constexpr int NBUCK = 196;    // ceil(NN / 512)
constexpr int NBLK  = 200;    // partition blocks
constexpr int CHUNK = 8000;   // NE / NBLK

typedef __attribute__((ext_vector_type(4))) float f32x4;
typedef __attribute__((ext_vector_type(8))) short bf16x8;
typedef __attribute__((ext_vector_type(8))) unsigned short u16x8;

__device__ __forceinline__ short f2bf(float f) {
    union { float f; unsigned u; } x; x.f = f;
    unsigned r = x.u + 0x7fffu + ((x.u >> 16) & 1u);   // RNE
    return (short)(r >> 16);
}
__device__ __forceinline__ float bf2f(short s) {
    union { unsigned u; float f; } x; x.u = ((unsigned)(unsigned short)s) << 16;
    return x.f;
}

__device__ __forceinline__ void wave_lds_fence() {
    __builtin_amdgcn_sched_barrier(0);
    asm volatile("s_waitcnt lgkmcnt(0)" ::: "memory");
    __builtin_amdgcn_sched_barrier(0);
}

// ---------------------------------------------------------------- CSR build
__global__ __launch_bounds__(256)
void bhist_kernel(const int* __restrict__ eidx, int* __restrict__ bcnt,
                  int* __restrict__ pbase) {
    __shared__ int lh[NBUCK];
    int b = blockIdx.x;
    for (int i = threadIdx.x; i < NBUCK; i += 256) lh[i] = 0;
    __syncthreads();
    int e0 = b * CHUNK;
    for (int i = threadIdx.x; i < CHUNK; i += 256)
        atomicAdd(&lh[eidx[NE + e0 + i] >> BSH], 1);
    __syncthreads();
    for (int i = threadIdx.x; i < NBUCK; i += 256)
        pbase[b * NBUCK + i] = atomicAdd(&bcnt[i], lh[i]);
}

__global__ void bscan_kernel(const int* __restrict__ bcnt, int* __restrict__ bbase,
                             int* __restrict__ offs) {
    __shared__ int lds[256];
    int t = threadIdx.x;
    int v = (t < NBUCK) ? bcnt[t] : 0;
    lds[t] = v; __syncthreads();
    #pragma unroll
    for (int o = 1; o < 256; o <<= 1) {
        int x = (t >= o) ? lds[t - o] : 0;
        __syncthreads();
        lds[t] += x;
        __syncthreads();
    }
    if (t < NBUCK) bbase[t] = lds[t] - v;
    if (t == 0) { bbase[NBUCK] = NE; offs[NN] = NE; }
}

__global__ __launch_bounds__(256)
void part_kernel(const int* __restrict__ eidx, const int* __restrict__ bbase,
                 const int* __restrict__ pbase, int2* __restrict__ tmp) {
    __shared__ int lh[NBUCK], lofs[NBUCK], lcnt[NBUCK], gb[NBUCK];
    __shared__ int sb[256];
    __shared__ int2 lp[CHUNK];
    int b = blockIdx.x;
    int t = threadIdx.x;
    for (int i = t; i < NBUCK; i += 256) { lh[i] = 0; lcnt[i] = 0; }
    __syncthreads();
    int e0 = b * CHUNK;
    for (int i = t; i < CHUNK; i += 256)
        atomicAdd(&lh[eidx[NE + e0 + i] >> BSH], 1);
    __syncthreads();
    {
        int v = (t < NBUCK) ? lh[t] : 0;
        sb[t] = v; __syncthreads();
        #pragma unroll
        for (int o = 1; o < 256; o <<= 1) {
            int x = (t >= o) ? sb[t - o] : 0;
            __syncthreads();
            sb[t] += x;
            __syncthreads();
        }
        if (t < NBUCK) {
            lofs[t] = sb[t] - v;
            gb[t]   = bbase[t] + pbase[b * NBUCK + t];
        }
    }
    __syncthreads();
    for (int i = t; i < CHUNK; i += 256) {
        int s = eidx[e0 + i], d = eidx[NE + e0 + i];
        int bk = d >> BSH;
        int r = atomicAdd(&lcnt[bk], 1);
        lp[lofs[bk] + r] = int2{s, d};
    }
    __syncthreads();
    for (int i = t; i < CHUNK; i += 256) {
        int2 p = lp[i];
        int bk = p.y >> BSH;
        tmp[gb[bk] + (i - lofs[bk])] = p;
    }
}

__global__ __launch_bounds__(512)
void bsort_kernel(const int* __restrict__ bbase, const int2* __restrict__ tmp,
                  int* __restrict__ offs, int* __restrict__ esrc) {
    __shared__ int h[512], lo[512], cnt[512];
    int bk = blockIdx.x;
    int n0 = bk << BSH;
    int lo0 = bbase[bk], hi0 = bbase[bk + 1];
    int t = threadIdx.x;
    h[t] = 0; cnt[t] = 0;
    __syncthreads();
    for (int i = lo0 + t; i < hi0; i += 512)
        atomicAdd(&h[tmp[i].y - n0], 1);
    __syncthreads();
    int v = h[t];
    lo[t] = v; __syncthreads();
    #pragma unroll
    for (int o = 1; o < 512; o <<= 1) {
        int x = (t >= o) ? lo[t - o] : 0;
        __syncthreads();
        lo[t] += x;
        __syncthreads();
    }
    int excl = lo[t] - v;
    __syncthreads();
    lo[t] = excl;
    __syncthreads();
    if (n0 + t < NN) offs[n0 + t] = lo0 + excl;
    for (int i = lo0 + t; i < hi0; i += 512) {
        int2 p = tmp[i];
        int ld = p.y - n0;
        int r = atomicAdd(&cnt[ld], 1);
        esrc[lo0 + lo[ld] + r] = p.x;
    }
}

// ---------------------------------------------------------------- x -> bf16
__global__ void cvt_kernel(const float* __restrict__ x, unsigned short* __restrict__ xb) {
    int i = blockIdx.x * 256 + threadIdx.x;       // ushort8 index
    if (i >= NN * DIN / 8) return;
    const f32x4* p = (const f32x4*)x + (size_t)i * 2;
    f32x4 v0 = p[0], v1 = p[1];
    u16x8 o;
    #pragma unroll
    for (int j = 0; j < 4; ++j) {
        o[j]     = (unsigned short)f2bf(v0[j]);
        o[j + 4] = (unsigned short)f2bf(v1[j]);
    }
    ((u16x8*)xb)[i] = o;
}

// ---------------------------------------------------------------- aggregation
// out[n] = (1+eps)*hf[n] + sum_{s in nbr(n)} hb[s]
// Next iteration's 8 indices are prefetched while gathers are in flight.
template<int D>
__global__ __launch_bounds__(256)
void aggb_kernel(const float* __restrict__ hf, const unsigned short* __restrict__ hb,
                 const int* __restrict__ offs, const int* __restrict__ esrc,
                 const float* __restrict__ epsp, float* __restrict__ out) {
    constexpr int TPN = D / 8;                 // lanes per node (ushort8 each)
    int node = blockIdx.x * (256 / TPN) + threadIdx.x / TPN;
    int f    = threadIdx.x % TPN;
    if (node >= NN) return;
    const u16x8* h8 = (const u16x8*)hb;
    float eps = 1.0f + *epsp;

    const float* hrow = hf + (size_t)node * D + f * 8;
    f32x4 a0 = *(const f32x4*)hrow * eps;
    f32x4 a1 = *(const f32x4*)(hrow + 4) * eps;
    f32x4 b0 = (f32x4)0.f, b1 = (f32x4)0.f;

    union { unsigned u; float fv; } cvt;
    auto acc8 = [&](u16x8 t, f32x4& x0, f32x4& x1) {
        #pragma unroll
        for (int j = 0; j < 4; ++j) { cvt.u = ((unsigned)t[j]) << 16;     x0[j] += cvt.fv; }
        #pragma unroll
        for (int j = 0; j < 4; ++j) { cvt.u = ((unsigned)t[j + 4]) << 16; x1[j] += cvt.fv; }
    };

    int k  = offs[node];
    int k1 = offs[node + 1];
    int kend8 = k + ((k1 - k) & ~7);

    int s[8];
    if (k < kend8) {
        #pragma unroll
        for (int j = 0; j < 8; ++j) s[j] = esrc[k + j];
    }
    while (k < kend8) {
        // gathers for current batch (issue immediately; indices already here)
        u16x8 t0 = h8[(size_t)s[0]*TPN+f], t1 = h8[(size_t)s[1]*TPN+f];
        u16x8 t2 = h8[(size_t)s[2]*TPN+f], t3 = h8[(size_t)s[3]*TPN+f];
        u16x8 t4 = h8[(size_t)s[4]*TPN+f], t5 = h8[(size_t)s[5]*TPN+f];
        u16x8 t6 = h8[(size_t)s[6]*TPN+f], t7 = h8[(size_t)s[7]*TPN+f];
        k += 8;
        // prefetch next batch's indices while gathers are in flight
        int sn[8];
        bool more = k < kend8;
        if (more) {
            #pragma unroll
            for (int j = 0; j < 8; ++j) sn[j] = esrc[k + j];
        }
        acc8(t0, a0, a1); acc8(t1, b0, b1); acc8(t2, a0, a1); acc8(t3, b0, b1);
        acc8(t4, a0, a1); acc8(t5, b0, b1); acc8(t6, a0, a1); acc8(t7, b0, b1);
        if (more) {
            #pragma unroll
            for (int j = 0; j < 8; ++j) s[j] = sn[j];
        }
    }
    for (; k + 2 <= k1; k += 2) {
        u16x8 t0 = h8[(size_t)esrc[k]*TPN+f];
        u16x8 t1 = h8[(size_t)esrc[k+1]*TPN+f];
        acc8(t0, a0, a1); acc8(t1, b0, b1);
    }
    if (k < k1) acc8(h8[(size_t)esrc[k]*TPN+f], a0, a1);

    float* orow = out + (size_t)node * D + f * 8;
    *(f32x4*)orow       = a0 + b0;
    *(f32x4*)(orow + 4) = a1 + b1;
}

// ---------------------------------------------------------------- weight pack
// frag: P[c][nt][lane][j] = bf16( W[c*32 + (lane>>4)*8 + j][nt*16 + (lane&15)] )
__global__ void packall_kernel(const float* __restrict__ W1a, const float* __restrict__ W1b,
                               const float* __restrict__ W2a, const float* __restrict__ W3a,
                               const float* __restrict__ W3b, const float* __restrict__ Wl,
                               short* P1a, short* P1b, short* P2a,
                               short* P3a, short* P3b, short* Pl) {
    const float* W; short* P; int K;
    switch (blockIdx.y) {
        case 0: W = W1a; P = P1a; K = 64;  break;
        case 1: W = W1b; P = P1b; K = 128; break;
        case 2: W = W2a; P = P2a; K = 128; break;
        case 3: W = W3a; P = P3a; K = 128; break;
        case 4: W = W3b; P = P3b; K = 128; break;
        default: W = Wl; P = Pl;  K = 128; break;
    }
    int T = (K / 32) * 8 * 64;
    int idx = blockIdx.x * 256 + threadIdx.x;
    if (idx >= T) return;
    int c  = idx >> 9;
    int nt = (idx >> 6) & 7;
    int l  = idx & 63;
    int col   = nt * 16 + (l & 15);
    int kbase = c * 32 + (l >> 4) * 8;
    bf16x8 hi, lo;
    #pragma unroll
    for (int j = 0; j < 8; ++j) {
        float w = W[(kbase + j) * HID + col];
        short h = f2bf(w);
        hi[j] = h;
        lo[j] = f2bf(w - bf2f(h));
    }
    *(bf16x8*)&P[(size_t)idx * 8]       = hi;
    *(bf16x8*)&P[(size_t)(T + idx) * 8] = lo;
}

// ---------------------------------------------------------------- single GEMM
// out = bn(relu(A@W + bias)); also writes bf16 copy hbout. 512 thr, 128 rows.
__global__ __launch_bounds__(512)
void gemm_bn_kernel(const float* __restrict__ A, const short* __restrict__ P,
                    const float* __restrict__ bias,
                    const float* __restrict__ g, const float* __restrict__ be,
                    const float* __restrict__ m, const float* __restrict__ v,
                    float* __restrict__ out, unsigned short* __restrict__ hbout, int M) {
    constexpr int NCH = 4;
    constexpr int T   = NCH * 8 * 64;
    __shared__ short wlds[2 * T * 8];

    const int tid  = threadIdx.x;
    const int wid  = tid >> 6;
    const int lane = tid & 63;

    for (int i = tid; i < 2 * T; i += 512)
        ((bf16x8*)wlds)[i] = ((const bf16x8*)P)[i];
    __syncthreads();

    const int rlo  = lane & 15;
    const int kgrp = lane >> 4;
    const int row  = blockIdx.x * 128 + wid * 16 + rlo;
    const int r    = row < M ? row : M - 1;
    const float* arow = A + (size_t)r * 128 + kgrp * 8;

    f32x4 acc[8];
    #pragma unroll
    for (int i = 0; i < 8; ++i) acc[i] = (f32x4)0.0f;

    #pragma unroll
    for (int c = 0; c < NCH; ++c) {
        f32x4 a0 = *(const f32x4*)(arow + c * 32);
        f32x4 a1 = *(const f32x4*)(arow + c * 32 + 4);
        bf16x8 ah, al;
        #pragma unroll
        for (int j = 0; j < 4; ++j) {
            short h0 = f2bf(a0[j]);
            short h1 = f2bf(a1[j]);
            ah[j]     = h0;
            ah[j + 4] = h1;
            al[j]     = f2bf(a0[j] - bf2f(h0));
            al[j + 4] = f2bf(a1[j] - bf2f(h1));
        }
        #pragma unroll
        for (int nt = 0; nt < 8; ++nt) {
            int fi = ((c * 8) + nt) * 64 + lane;
            bf16x8 wh = *(bf16x8*)&wlds[(size_t)fi * 8];
            bf16x8 wl = *(bf16x8*)&wlds[(size_t)(T + fi) * 8];
            acc[nt] = __builtin_amdgcn_mfma_f32_16x16x32_bf16(ah, wh, acc[nt], 0, 0, 0);
            acc[nt] = __builtin_amdgcn_mfma_f32_16x16x32_bf16(al, wh, acc[nt], 0, 0, 0);
            acc[nt] = __builtin_amdgcn_mfma_f32_16x16x32_bf16(ah, wl, acc[nt], 0, 0, 0);
        }
    }

    #pragma unroll
    for (int nt = 0; nt < 8; ++nt) {
        int col  = nt * 16 + rlo;
        float bb = bias[col];
        float sv = g[col] * rsqrtf(v[col] + 1e-5f);
        float tv = be[col] - m[col] * sv;
        #pragma unroll
        for (int jj = 0; jj < 4; ++jj) {
            int rr = blockIdx.x * 128 + wid * 16 + kgrp * 4 + jj;
            float val = fmaxf(acc[nt][jj] + bb, 0.f) * sv + tv;
            if (rr < M) {
                out[(size_t)rr * 128 + col] = val;
                hbout[(size_t)rr * 128 + col] = (unsigned short)f2bf(val);
            }
        }
    }
}

// ---------------------------------------------------------------- fused pair
// out = bn(relu( relu(A@W1 + b1) @ W2 + b2 ));  bf16 copy to hbout.
// 128 threads (2 waves), 64 rows/block; each wave computes 2 tiles (rows
// wid*16 and wid*16+32) reusing each W-fragment pair for 6 MFMAs.
template<int K1>
__global__ __launch_bounds__(128)
void fused2_kernel(const float* __restrict__ A,
                   const short* __restrict__ P1, const float* __restrict__ bias1,
                   const short* __restrict__ P2, const float* __restrict__ bias2,
                   const float* __restrict__ g, const float* __restrict__ be,
                   const float* __restrict__ m, const float* __restrict__ v,
                   float* __restrict__ out, unsigned short* __restrict__ hbout, int M) {
    constexpr int NCH1 = K1 / 32;
    constexpr int T1   = NCH1 * 8 * 64;
    constexpr int T2   = 4 * 8 * 64;
    constexpr int LDW  = 136;
    __shared__ short h1hi[64 * LDW];
    __shared__ short h1lo[64 * LDW];

    const int tid  = threadIdx.x;
    const int wid  = tid >> 6;          // 0..1
    const int lane = tid & 63;
    const int rlo  = lane & 15;
    const int kgrp = lane >> 4;

    const int rowA = blockIdx.x * 64 + wid * 16 + rlo;
    const int rowB = rowA + 32;
    const int rA   = rowA < M ? rowA : M - 1;
    const int rB   = rowB < M ? rowB : M - 1;
    const float* arowA = A + (size_t)rA * K1 + kgrp * 8;
    const float* arowB = A + (size_t)rB * K1 + kgrp * 8;

    const bf16x8* P1v = (const bf16x8*)P1;
    const bf16x8* P2v = (const bf16x8*)P2;

    f32x4 accA[8], accB[8];
    #pragma unroll
    for (int i = 0; i < 8; ++i) { accA[i] = (f32x4)0.0f; accB[i] = (f32x4)0.0f; }

    // ---- stage 1
    #pragma unroll
    for (int c = 0; c < NCH1; ++c) {
        f32x4 aA0 = *(const f32x4*)(arowA + c * 32);
        f32x4 aA1 = *(const f32x4*)(arowA + c * 32 + 4);
        f32x4 aB0 = *(const f32x4*)(arowB + c * 32);
        f32x4 aB1 = *(const f32x4*)(arowB + c * 32 + 4);
        bf16x8 ahA, alA, ahB, alB;
        #pragma unroll
        for (int j = 0; j < 4; ++j) {
            short h;
            h = f2bf(aA0[j]); ahA[j]   = h; alA[j]   = f2bf(aA0[j] - bf2f(h));
            h = f2bf(aA1[j]); ahA[j+4] = h; alA[j+4] = f2bf(aA1[j] - bf2f(h));
            h = f2bf(aB0[j]); ahB[j]   = h; alB[j]   = f2bf(aB0[j] - bf2f(h));
            h = f2bf(aB1[j]); ahB[j+4] = h; alB[j+4] = f2bf(aB1[j] - bf2f(h));
        }
        #pragma unroll
        for (int nt = 0; nt < 8; ++nt) {
            int fi = ((c * 8) + nt) * 64 + lane;
            bf16x8 wh = P1v[fi];
            bf16x8 wl = P1v[T1 + fi];
            accA[nt] = __builtin_amdgcn_mfma_f32_16x16x32_bf16(ahA, wh, accA[nt], 0, 0, 0);
            accA[nt] = __builtin_amdgcn_mfma_f32_16x16x32_bf16(alA, wh, accA[nt], 0, 0, 0);
            accA[nt] = __builtin_amdgcn_mfma_f32_16x16x32_bf16(ahA, wl, accA[nt], 0, 0, 0);
            accB[nt] = __builtin_amdgcn_mfma_f32_16x16x32_bf16(ahB, wh, accB[nt], 0, 0, 0);
            accB[nt] = __builtin_amdgcn_mfma_f32_16x16x32_bf16(alB, wh, accB[nt], 0, 0, 0);
            accB[nt] = __builtin_amdgcn_mfma_f32_16x16x32_bf16(ahB, wl, accB[nt], 0, 0, 0);
        }
    }

    // ---- epilogue 1: relu(+b1) -> LDS (both tiles)
    #pragma unroll
    for (int nt = 0; nt < 8; ++nt) {
        int col  = nt * 16 + rlo;
        float bb = bias1[col];
        #pragma unroll
        for (int jj = 0; jj < 4; ++jj) {
            int lrA = wid * 16 + kgrp * 4 + jj;
            float vA = fmaxf(accA[nt][jj] + bb, 0.f);
            short hA = f2bf(vA);
            h1hi[lrA * LDW + col] = hA;
            h1lo[lrA * LDW + col] = f2bf(vA - bf2f(hA));
            int lrB = lrA + 32;
            float vB = fmaxf(accB[nt][jj] + bb, 0.f);
            short hB = f2bf(vB);
            h1hi[lrB * LDW + col] = hB;
            h1lo[lrB * LDW + col] = f2bf(vB - bf2f(hB));
        }
    }
    wave_lds_fence();

    // ---- stage 2
    #pragma unroll
    for (int i = 0; i < 8; ++i) { accA[i] = (f32x4)0.0f; accB[i] = (f32x4)0.0f; }
    const int lrA2 = wid * 16 + rlo;
    const int lrB2 = lrA2 + 32;
    #pragma unroll
    for (int c = 0; c < 4; ++c) {
        bf16x8 ahA = *(bf16x8*)&h1hi[lrA2 * LDW + c * 32 + kgrp * 8];
        bf16x8 alA = *(bf16x8*)&h1lo[lrA2 * LDW + c * 32 + kgrp * 8];
        bf16x8 ahB = *(bf16x8*)&h1hi[lrB2 * LDW + c * 32 + kgrp * 8];
        bf16x8 alB = *(bf16x8*)&h1lo[lrB2 * LDW + c * 32 + kgrp * 8];
        #pragma unroll
        for (int nt = 0; nt < 8; ++nt) {
            int fi = ((c * 8) + nt) * 64 + lane;
            bf16x8 wh = P2v[fi];
            bf16x8 wl = P2v[T2 + fi];
            accA[nt] = __builtin_amdgcn_mfma_f32_16x16x32_bf16(ahA, wh, accA[nt], 0, 0, 0);
            accA[nt] = __builtin_amdgcn_mfma_f32_16x16x32_bf16(alA, wh, accA[nt], 0, 0, 0);
            accA[nt] = __builtin_amdgcn_mfma_f32_16x16x32_bf16(ahA, wl, accA[nt], 0, 0, 0);
            accB[nt] = __builtin_amdgcn_mfma_f32_16x16x32_bf16(ahB, wh, accB[nt], 0, 0, 0);
            accB[nt] = __builtin_amdgcn_mfma_f32_16x16x32_bf16(alB, wh, accB[nt], 0, 0, 0);
            accB[nt] = __builtin_amdgcn_mfma_f32_16x16x32_bf16(ahB, wl, accB[nt], 0, 0, 0);
        }
    }

    // ---- epilogue 2: bn(relu(+b2)) -> global (both tiles)
    #pragma unroll
    for (int nt = 0; nt < 8; ++nt) {
        int col  = nt * 16 + rlo;
        float bb = bias2[col];
        float sv = g[col] * rsqrtf(v[col] + 1e-5f);
        float tv = be[col] - m[col] * sv;
        #pragma unroll
        for (int jj = 0; jj < 4; ++jj) {
            int rrA = blockIdx.x * 64 + wid * 16 + kgrp * 4 + jj;
            float vA = fmaxf(accA[nt][jj] + bb, 0.f) * sv + tv;
            if (rrA < M) {
                out[(size_t)rrA * 128 + col] = vA;
                hbout[(size_t)rrA * 128 + col] = (unsigned short)f2bf(vA);
            }
            int rrB = rrA + 32;
            float vB = fmaxf(accB[nt][jj] + bb, 0.f) * sv + tv;
            if (rrB < M) {
                out[(size_t)rrB * 128 + col] = vB;
                hbout[(size_t)rrB * 128 + col] = (unsigned short)f2bf(vB);
            }
        }
    }
}

// ---------------------------------------------------------------- fused L3+head
// out[r] = dot(relu( bn(relu( relu(A@W3a+b3a) @ W3b + b3b )) @ Wl + bl ), Wf) + bf
// Same 2-tile-per-wave structure, 3 GEMM stages.
__global__ __launch_bounds__(128)
void fused3_kernel(const float* __restrict__ A,
                   const short* __restrict__ P1, const float* __restrict__ bias1,
                   const short* __restrict__ P2, const float* __restrict__ bias2,
                   const float* __restrict__ g, const float* __restrict__ be,
                   const float* __restrict__ m, const float* __restrict__ v,
                   const short* __restrict__ Pl, const float* __restrict__ bl,
                   const float* __restrict__ Wf, const float* __restrict__ bf,
                   float* __restrict__ out, int M) {
    constexpr int T  = 4 * 8 * 64;
    constexpr int LDW = 136;
    __shared__ short h1hi[64 * LDW];
    __shared__ short h1lo[64 * LDW];

    const int tid  = threadIdx.x;
    const int wid  = tid >> 6;
    const int lane = tid & 63;
    const int rlo  = lane & 15;
    const int kgrp = lane >> 4;

    const int rowA = blockIdx.x * 64 + wid * 16 + rlo;
    const int rowB = rowA + 32;
    const int rA   = rowA < M ? rowA : M - 1;
    const int rB   = rowB < M ? rowB : M - 1;
    const float* arowA = A + (size_t)rA * 128 + kgrp * 8;
    const float* arowB = A + (size_t)rB * 128 + kgrp * 8;

    const bf16x8* P1v = (const bf16x8*)P1;
    const bf16x8* P2v = (const bf16x8*)P2;
    const bf16x8* Plv = (const bf16x8*)Pl;

    f32x4 accA[8], accB[8];
    #pragma unroll
    for (int i = 0; i < 8; ++i) { accA[i] = (f32x4)0.0f; accB[i] = (f32x4)0.0f; }

    // ---- stage 1: relu(A@W3a + b3a) -> LDS
    #pragma unroll
    for (int c = 0; c < 4; ++c) {
        f32x4 aA0 = *(const f32x4*)(arowA + c * 32);
        f32x4 aA1 = *(const f32x4*)(arowA + c * 32 + 4);
        f32x4 aB0 = *(const f32x4*)(arowB + c * 32);
        f32x4 aB1 = *(const f32x4*)(arowB + c * 32 + 4);
        bf16x8 ahA, alA, ahB, alB;
        #pragma unroll
        for (int j = 0; j < 4; ++j) {
            short h;
            h = f2bf(aA0[j]); ahA[j]   = h; alA[j]   = f2bf(aA0[j] - bf2f(h));
            h = f2bf(aA1[j]); ahA[j+4] = h; alA[j+4] = f2bf(aA1[j] - bf2f(h));
            h = f2bf(aB0[j]); ahB[j]   = h; alB[j]   = f2bf(aB0[j] - bf2f(h));
            h = f2bf(aB1[j]); ahB[j+4] = h; alB[j+4] = f2bf(aB1[j] - bf2f(h));
        }
        #pragma unroll
        for (int nt = 0; nt < 8; ++nt) {
            int fi = ((c * 8) + nt) * 64 + lane;
            bf16x8 wh = P1v[fi];
            bf16x8 wl = P1v[T + fi];
            accA[nt] = __builtin_amdgcn_mfma_f32_16x16x32_bf16(ahA, wh, accA[nt], 0, 0, 0);
            accA[nt] = __builtin_amdgcn_mfma_f32_16x16x32_bf16(alA, wh, accA[nt], 0, 0, 0);
            accA[nt] = __builtin_amdgcn_mfma_f32_16x16x32_bf16(ahA, wl, accA[nt], 0, 0, 0);
            accB[nt] = __builtin_amdgcn_mfma_f32_16x16x32_bf16(ahB, wh, accB[nt], 0, 0, 0);
            accB[nt] = __builtin_amdgcn_mfma_f32_16x16x32_bf16(alB, wh, accB[nt], 0, 0, 0);
            accB[nt] = __builtin_amdgcn_mfma_f32_16x16x32_bf16(ahB, wl, accB[nt], 0, 0, 0);
        }
    }
    #pragma unroll
    for (int nt = 0; nt < 8; ++nt) {
        int col  = nt * 16 + rlo;
        float bb = bias1[col];
        #pragma unroll
        for (int jj = 0; jj < 4; ++jj) {
            int lrA = wid * 16 + kgrp * 4 + jj;
            float vA = fmaxf(accA[nt][jj] + bb, 0.f);
            short hA = f2bf(vA);
            h1hi[lrA * LDW + col] = hA;
            h1lo[lrA * LDW + col] = f2bf(vA - bf2f(hA));
            int lrB = lrA + 32;
            float vB = fmaxf(accB[nt][jj] + bb, 0.f);
            short hB = f2bf(vB);
            h1hi[lrB * LDW + col] = hB;
            h1lo[lrB * LDW + col] = f2bf(vB - bf2f(hB));
        }
    }
    wave_lds_fence();

    // ---- stage 2: bn(relu(h1@W3b + b3b)) -> LDS (reuse planes; wave-local
    //      in-order LDS makes read-before-overwrite safe)
    const int lrA2 = wid * 16 + rlo;
    const int lrB2 = lrA2 + 32;
    #pragma unroll
    for (int i = 0; i < 8; ++i) { accA[i] = (f32x4)0.0f; accB[i] = (f32x4)0.0f; }
    #pragma unroll
    for (int c = 0; c < 4; ++c) {
        bf16x8 ahA = *(bf16x8*)&h1hi[lrA2 * LDW + c * 32 + kgrp * 8];
        bf16x8 alA = *(bf16x8*)&h1lo[lrA2 * LDW + c * 32 + kgrp * 8];
        bf16x8 ahB = *(bf16x8*)&h1hi[lrB2 * LDW + c * 32 + kgrp * 8];
        bf16x8 alB = *(bf16x8*)&h1lo[lrB2 * LDW + c * 32 + kgrp * 8];
        #pragma unroll
        for (int nt = 0; nt < 8; ++nt) {
            int fi = ((c * 8) + nt) * 64 + lane;
            bf16x8 wh = P2v[fi];
            bf16x8 wl = P2v[T + fi];
            accA[nt] = __builtin_amdgcn_mfma_f32_16x16x32_bf16(ahA, wh, accA[nt], 0, 0, 0);
            accA[nt] = __builtin_amdgcn_mfma_f32_16x16x32_bf16(alA, wh, accA[nt], 0, 0, 0);
            accA[nt] = __builtin_amdgcn_mfma_f32_16x16x32_bf16(ahA, wl, accA[nt], 0, 0, 0);
            accB[nt] = __builtin_amdgcn_mfma_f32_16x16x32_bf16(ahB, wh, accB[nt], 0, 0, 0);
            accB[nt] = __builtin_amdgcn_mfma_f32_16x16x32_bf16(alB, wh, accB[nt], 0, 0, 0);
            accB[nt] = __builtin_amdgcn_mfma_f32_16x16x32_bf16(ahB, wl, accB[nt], 0, 0, 0);
        }
    }
    wave_lds_fence();
    #pragma unroll
    for (int nt = 0; nt < 8; ++nt) {
        int col  = nt * 16 + rlo;
        float bb = bias2[col];
        float sv = g[col] * rsqrtf(v[col] + 1e-5f);
        float tv = be[col] - m[col] * sv;
        #pragma unroll
        for (int jj = 0; jj < 4; ++jj) {
            int lrA = wid * 16 + kgrp * 4 + jj;
            float vA = fmaxf(accA[nt][jj] + bb, 0.f) * sv + tv;
            short hA = f2bf(vA);
            h1hi[lrA * LDW + col] = hA;
            h1lo[lrA * LDW + col] = f2bf(vA - bf2f(hA));
            int lrB = lrA + 32;
            float vB = fmaxf(accB[nt][jj] + bb, 0.f) * sv + tv;
            short hB = f2bf(vB);
            h1hi[lrB * LDW + col] = hB;
            h1lo[lrB * LDW + col] = f2bf(vB - bf2f(hB));
        }
    }
    wave_lds_fence();

    // ---- stage 3: relu(h2@Wl + bl) . Wf + bf -> out
    #pragma unroll
    for (int i = 0; i < 8; ++i) { accA[i] = (f32x4)0.0f; accB[i] = (f32x4)0.0f; }
    #pragma unroll
    for (int c = 0; c < 4; ++c) {
        bf16x8 ahA = *(bf16x8*)&h1hi[lrA2 * LDW + c * 32 + kgrp * 8];
        bf16x8 alA = *(bf16x8*)&h1lo[lrA2 * LDW + c * 32 + kgrp * 8];
        bf16x8 ahB = *(bf16x8*)&h1hi[lrB2 * LDW + c * 32 + kgrp * 8];
        bf16x8 alB = *(bf16x8*)&h1lo[lrB2 * LDW + c * 32 + kgrp * 8];
        #pragma unroll
        for (int nt = 0; nt < 8; ++nt) {
            int fi = ((c * 8) + nt) * 64 + lane;
            bf16x8 wh = Plv[fi];
            bf16x8 wl = Plv[T + fi];
            accA[nt] = __builtin_amdgcn_mfma_f32_16x16x32_bf16(ahA, wh, accA[nt], 0, 0, 0);
            accA[nt] = __builtin_amdgcn_mfma_f32_16x16x32_bf16(alA, wh, accA[nt], 0, 0, 0);
            accA[nt] = __builtin_amdgcn_mfma_f32_16x16x32_bf16(ahA, wl, accA[nt], 0, 0, 0);
            accB[nt] = __builtin_amdgcn_mfma_f32_16x16x32_bf16(ahB, wh, accB[nt], 0, 0, 0);
            accB[nt] = __builtin_amdgcn_mfma_f32_16x16x32_bf16(alB, wh, accB[nt], 0, 0, 0);
            accB[nt] = __builtin_amdgcn_mfma_f32_16x16x32_bf16(ahB, wl, accB[nt], 0, 0, 0);
        }
    }
    float pA0 = 0, pA1 = 0, pA2 = 0, pA3 = 0;
    float pB0 = 0, pB1 = 0, pB2 = 0, pB3 = 0;
    #pragma unroll
    for (int nt = 0; nt < 8; ++nt) {
        int col  = nt * 16 + rlo;
        float bb = bl[col];
        float wv = Wf[col];
        pA0 += fmaxf(accA[nt][0] + bb, 0.f) * wv;
        pA1 += fmaxf(accA[nt][1] + bb, 0.f) * wv;
        pA2 += fmaxf(accA[nt][2] + bb, 0.f) * wv;
        pA3 += fmaxf(accA[nt][3] + bb, 0.f) * wv;
        pB0 += fmaxf(accB[nt][0] + bb, 0.f) * wv;
        pB1 += fmaxf(accB[nt][1] + bb, 0.f) * wv;
        pB2 += fmaxf(accB[nt][2] + bb, 0.f) * wv;
        pB3 += fmaxf(accB[nt][3] + bb, 0.f) * wv;
    }
    #pragma unroll
    for (int o = 1; o < 16; o <<= 1) {
        pA0 += __shfl_xor(pA0, o); pA1 += __shfl_xor(pA1, o);
        pA2 += __shfl_xor(pA2, o); pA3 += __shfl_xor(pA3, o);
        pB0 += __shfl_xor(pB0, o); pB1 += __shfl_xor(pB1, o);
        pB2 += __shfl_xor(pB2, o); pB3 += __shfl_xor(pB3, o);
    }
    if (rlo == 0) {
        int rbase = blockIdx.x * 64 + wid * 16 + kgrp * 4;
        float bfv = bf[0];
        if (rbase + 0 < M) out[rbase + 0] = pA0 + bfv;
        if (rbase + 1 < M) out[rbase + 1] = pA1 + bfv;
        if (rbase + 2 < M) out[rbase + 2] = pA2 + bfv;
        if (rbase + 3 < M) out[rbase + 3] = pA3 + bfv;
        int rb2 = rbase + 32;
        if (rb2 + 0 < M) out[rb2 + 0] = pB0 + bfv;
        if (rb2 + 1 < M) out[rb2 + 1] = pB1 + bfv;
        if (rb2 + 2 < M) out[rb2 + 2] = pB2 + bfv;
        if (rb2 + 3 < M) out[rb2 + 3] = pB3 + bfv;
    }
}

// ---------------------------------------------------------------------------
extern "C" void kernel_launch(void* const* d_in, const int* in_sizes, int n_in,
                              void* d_out, int out_size, void* d_ws, size_t ws_size,
                              hipStream_t stream) {
    const float* x    = (const float*)d_in[0];
    const int*   eidx = (const int*)d_in[1];
    const float* eps1 = (const float*)d_in[2];
    const float* W1a  = (const float*)d_in[3];
    const float* b1a  = (const float*)d_in[4];
    const float* W1b  = (const float*)d_in[5];
    const float* b1b  = (const float*)d_in[6];
    const float* g1   = (const float*)d_in[7];
    const float* be1  = (const float*)d_in[8];
    const float* m1   = (const float*)d_in[9];
    const float* v1   = (const float*)d_in[10];
    const float* eps2 = (const float*)d_in[11];
    const float* W2a  = (const float*)d_in[12];
    const float* b2a  = (const float*)d_in[13];
    const float* g2   = (const float*)d_in[14];
    const float* be2  = (const float*)d_in[15];
    const float* m2   = (const float*)d_in[16];
    const float* v2   = (const float*)d_in[17];
    const float* eps3 = (const float*)d_in[18];
    const float* W3a  = (const float*)d_in[19];
    const float* b3a  = (const float*)d_in[20];
    const float* W3b  = (const float*)d_in[21];
    const float* b3b  = (const float*)d_in[22];
    const float* g3   = (const float*)d_in[23];
    const float* be3  = (const float*)d_in[24];
    const float* m3   = (const float*)d_in[25];
    const float* v3   = (const float*)d_in[26];
    const float* Wl   = (const float*)d_in[27];
    const float* bl   = (const float*)d_in[28];
    const float* Wf   = (const float*)d_in[29];
    const float* bfp  = (const float*)d_in[30];

    char* ws = (char*)d_ws;
    size_t off = 0;
    auto alloc = [&](size_t bytes) -> void* {
        off = (off + 255) & ~(size_t)255;
        void* p = ws + off;
        off += bytes;
        return p;
    };

    float*          bufA = (float*)alloc((size_t)NN * 128 * 4);
    float*          bufB = (float*)alloc((size_t)NN * 128 * 4);
    unsigned short* hb   = (unsigned short*)alloc((size_t)NN * 128 * 2);
    int*   offs   = (int*)alloc((size_t)(NN + 1) * 4);
    int*   esrc   = (int*)alloc((size_t)NE * 4);
    int*   bcnt   = (int*)alloc((size_t)NBUCK * 4);
    int*   bbase  = (int*)alloc((size_t)(NBUCK + 1) * 4);
    int*   pbase  = (int*)alloc((size_t)NBLK * NBUCK * 4);
    short* P1a    = (short*)alloc((size_t)2 * DIN * HID * 2);
    short* P1b    = (short*)alloc((size_t)2 * HID * HID * 2);
    short* P2a    = (short*)alloc((size_t)2 * HID * HID * 2);
    short* P3a    = (short*)alloc((size_t)2 * HID * HID * 2);
    short* P3b    = (short*)alloc((size_t)2 * HID * HID * 2);
    short* Pl     = (short*)alloc((size_t)2 * HID * HID * 2);
    // tmp edge pairs (12.8 MB) alias bufA: only live during CSR build.
    int2*  tmp    = (int2*)bufA;

    const int GRID_G    = (NN + 127) / 128;         // gemm_bn, 128 rows
    const int GRID_F    = (NN + 63) / 64;           // fused, 64 rows (2 waves x 2 tiles)
    const int GRID_A64  = (NN + 31) / 32;           // aggb<64>: 32 nodes/block
    const int GRID_A128 = (NN + 15) / 16;           // aggb<128>: 16 nodes/block

    // ---- CSR build (2-level counting sort)
    hipMemsetAsync(bcnt, 0, (size_t)NBUCK * 4, stream);
    bhist_kernel<<<NBLK, 256, 0, stream>>>(eidx, bcnt, pbase);
    bscan_kernel<<<1, 256, 0, stream>>>(bcnt, bbase, offs);
    part_kernel<<<NBLK, 256, 0, stream>>>(eidx, bbase, pbase, tmp);
    bsort_kernel<<<NBUCK, 512, 0, stream>>>(bbase, tmp, offs, esrc);

    // ---- pack weights + bf16 x
    {
        dim3 grid(8, 6);
        packall_kernel<<<grid, 256, 0, stream>>>(W1a, W1b, W2a, W3a, W3b, Wl,
                                                 P1a, P1b, P2a, P3a, P3b, Pl);
    }
    cvt_kernel<<<(NN * DIN / 8 + 255) / 256, 256, 0, stream>>>(x, hb);

    // ---- layer 1 (agg -> fused W1a+W1b+BN)
    aggb_kernel<64><<<GRID_A64, 256, 0, stream>>>(x, hb, offs, esrc, eps1, bufA);
    fused2_kernel<64><<<GRID_F, 128, 0, stream>>>(bufA, P1a, b1a, P1b, b1b,
                                                  g1, be1, m1, v1, bufB, hb, NN);
    // ---- layer 2 (agg -> single GEMM+BN)
    aggb_kernel<128><<<GRID_A128, 256, 0, stream>>>(bufB, hb, offs, esrc, eps2, bufA);
    gemm_bn_kernel<<<GRID_G, 512, 0, stream>>>(bufA, P2a, b2a, g2, be2, m2, v2,
                                               bufB, hb, NN);
    // ---- layer 3 + head (agg -> fused W3a+W3b+BN+Wl+Wf)
    aggb_kernel<128><<<GRID_A128, 256, 0, stream>>>(bufB, hb, offs, esrc, eps3, bufA);
    fused3_kernel<<<GRID_F, 128, 0, stream>>>(bufA, P3a, b3a, P3b, b3b,
                                              g3, be3, m3, v3, Pl, bl, Wf, bfp,
                                              (float*)d_out, NN);
}